// Round 1
// baseline (791.191 us; speedup 1.0000x reference)
//
#include <hip/hip_runtime.h>
#include <cstdint>
#include <cstddef>

#define HD 128
#define NEG_SLOPE 0.2f
#define BN_EPS 1e-5f

typedef __bf16 bf16x8 __attribute__((ext_vector_type(8)));
typedef float  f32x4  __attribute__((ext_vector_type(4)));

__device__ __forceinline__ unsigned short f2b(float f) {   // fp32 -> bf16 RNE
    unsigned int u = __float_as_uint(f);
    u = (u + 0x7fffu + ((u >> 16) & 1u)) >> 16;
    return (unsigned short)u;
}
__device__ __forceinline__ unsigned int pack2(float lo, float hi) {
    return (unsigned int)f2b(lo) | ((unsigned int)f2b(hi) << 16);
}

// async global->LDS, 16B per lane; LDS dest is wave-uniform base + lane*16
__device__ __forceinline__ void gload_lds16(const void* g, void* l) {
    __builtin_amdgcn_global_load_lds(
        (const __attribute__((address_space(1))) uint32_t*)g,
        (__attribute__((address_space(3))) uint32_t*)l, 16, 0, 0);
}

// =============================================================================
// Weight prep: gw,fw fp32 [K][128] -> Wt bf16 [256][K]  (cols 0..127 = gw,
// 128..255 = fw; cast + transpose, tiny)
// =============================================================================
__global__ void prep_w2(const float* __restrict__ gw, const float* __restrict__ fw,
                        unsigned short* __restrict__ Wt, int K)
{
    int t = blockIdx.x * 256 + threadIdx.x;
    if (t >= K * 256) return;
    int k = t >> 8, c = t & 255;
    float v = (c < 128) ? gw[(size_t)k * 128 + c] : fw[(size_t)k * 128 + (c - 128)];
    Wt[(size_t)c * K + k] = f2b(v);
}

// =============================================================================
// Fused dual GEMM (m97 structure): [h | y][M,256] = X[M,K] @ Wt[256,K]
// Tile 64(M) x 256(N), BK=32, 256 thr = 4 waves, wave = 64x64 slab
// = 4x4 16x16 tiles -> 16 MFMA + 12 ds_read_b128 per K-step.
// Staging via global_load_lds dwordx4 (no VGPR round-trip, no prefetch regs):
// latency drains at the pre-barrier vmcnt(0); hidden by ~4 resident blocks/CU
// (grid = 1250 blocks vs old 625 -> 2x TLP; this was the R-prev MfmaUtil=7%
// latency wall, NOT bank conflicts: 4.48M conflict-cyc = 0.002% of dispatch).
// LDS is LINEAR (gload_lds requirement) + both-sides XOR swizzle (rule #21):
//   A fp32 [64][128B]: off ^ ((row&7)<<4)      -> 2-way on ds_read_b128 (free)
//   B bf16 [256][64B]: off ^ (((row>>1)&3)<<4) -> 2-way (free)
// applied to the per-lane GLOBAL source at stage time and the LDS read addr.
// fp32->bf16 pack moved to read side (16 pack2/wave-step, negligible).
// Frag layouts (verified R3/R4): A[m=lane&15][k=q*8+j], B[k=q*8+j][n=lane&15],
// D col=lane&15, row=q*4+reg.  h cols (w<2) -> bf16; y cols (w>=2) -> fp32
// relu((acc+fb)*g+fbeta)+gb.
// =============================================================================
__global__ __launch_bounds__(256, 4) void gemm_dual(
    const float* __restrict__ X, const unsigned short* __restrict__ Wt,
    unsigned short* __restrict__ hb, float* __restrict__ yb, int M, int K,
    const float* __restrict__ fb, const float* __restrict__ fg,
    const float* __restrict__ fbeta, const float* __restrict__ gb)
{
    __shared__ __align__(16) char smem[64 * 128 + 256 * 64];   // 24.5 KB
    char* Asb = smem;              // A: 64 rows x 32 fp32 (128B), swizzled
    char* Bsb = smem + 64 * 128;   // B: 256 rows x 32 bf16 (64B), swizzled

    const int tid  = threadIdx.x;
    const int lane = tid & 63, w = tid >> 6;
    const int row0 = blockIdx.x * 64;
    const int m = lane & 15, q = lane >> 4;

    // ---- staging source addresses (inverse-swizzled per lane) ----
    const int la = lane >> 3, ca = lane & 7;     // A: 8 lanes cover one 128B row
    const int lb = lane >> 2, cb = lane & 3;     // B: 4 lanes cover one 64B row
    const int oA = 4 * (ca ^ la);                // float offset inside 32-chunk
    const int oB = 8 * (cb ^ (la & 3));          // short offset inside 32-chunk

    const float* ap[2];
    const unsigned short* bp[4];
#pragma unroll
    for (int i = 0; i < 2; i++) {
        int r  = (i * 4 + w) * 8 + la;           // LDS row 0..63
        int gr = row0 + r; if (gr >= M) gr = M - 1;
        ap[i] = X + (size_t)gr * K + oA;
    }
#pragma unroll
    for (int i = 0; i < 4; i++) {
        int r = (i * 4 + w) * 16 + lb;           // LDS row 0..255 (= out col)
        bp[i] = Wt + (size_t)r * K + oB;
    }

    f32x4 acc[4][4];
#pragma unroll
    for (int rt = 0; rt < 4; rt++)
#pragma unroll
        for (int ct = 0; ct < 4; ct++) acc[rt][ct] = (f32x4){0.f, 0.f, 0.f, 0.f};

    for (int ks = 0; ks < K; ks += 32) {
        __syncthreads();                         // prev-step LDS reads done
#pragma unroll
        for (int i = 0; i < 2; i++)
            gload_lds16(ap[i] + ks, Asb + (i * 4 + w) * 1024);
#pragma unroll
        for (int i = 0; i < 4; i++)
            gload_lds16(bp[i] + ks, Bsb + (i * 4 + w) * 1024);
        __syncthreads();                         // vmcnt(0) drain -> tile ready

        bf16x8 af[4], bfr[4];
#pragma unroll
        for (int rt = 0; rt < 4; rt++) {
            int row = rt * 16 + m;
            const char* base = Asb + (row << 7);
            int sw = (m & 7) << 4;
            f32x4 a0 = *(const f32x4*)(base + ((q * 32)      ^ sw));
            f32x4 a1 = *(const f32x4*)(base + ((q * 32 + 16) ^ sw));
            uint4 av;
            av.x = pack2(a0.x, a0.y); av.y = pack2(a0.z, a0.w);
            av.z = pack2(a1.x, a1.y); av.w = pack2(a1.z, a1.w);
            af[rt] = *(bf16x8*)&av;
        }
#pragma unroll
        for (int ct = 0; ct < 4; ct++) {
            int row = w * 64 + ct * 16 + m;
            bfr[ct] = *(const bf16x8*)(Bsb + (row << 6) +
                                       ((q * 16) ^ (((m >> 1) & 3) << 4)));
        }
#pragma unroll
        for (int rt = 0; rt < 4; rt++)
#pragma unroll
            for (int ct = 0; ct < 4; ct++)
                acc[rt][ct] = __builtin_amdgcn_mfma_f32_16x16x32_bf16(af[rt], bfr[ct], acc[rt][ct], 0, 0, 0);
    }

    // epilogue: D[row = row0+rt*16+q*4+r][gcol = 64*w+ct*16+m]
    if (w < 2) {               // h half, bf16
#pragma unroll
        for (int ct = 0; ct < 4; ct++) {
            int col = 64 * w + ct * 16 + m;
#pragma unroll
            for (int rt = 0; rt < 4; rt++)
#pragma unroll
                for (int r = 0; r < 4; r++) {
                    int row = row0 + rt * 16 + q * 4 + r;
                    if (row < M) hb[(size_t)row * HD + col] = f2b(acc[rt][ct][r]);
                }
        }
    } else {                   // y half, fp32 with BN+relu+gb
        const float inv_bn = 1.0f / sqrtf(1.0f + BN_EPS);
#pragma unroll
        for (int ct = 0; ct < 4; ct++) {
            int col = 64 * (w - 2) + ct * 16 + m;
            float g  = fg[col] * inv_bn;
            float bb = fb[col];
            float bt = fbeta[col];
            float gv = gb[col];
#pragma unroll
            for (int rt = 0; rt < 4; rt++)
#pragma unroll
                for (int r = 0; r < 4; r++) {
                    int row = row0 + rt * 16 + q * 4 + r;
                    if (row < M) {
                        float y = (acc[rt][ct][r] + bb) * g + bt;
                        y = y > 0.f ? y : 0.f;       // feature_transform relu
                        yb[(size_t)row * HD + col] = y + gv;
                    }
                }
        }
    }
}

// ============================ attention logits ===============================
__global__ void al_kernel(const unsigned short* __restrict__ h,
                          const float* __restrict__ a_src, const float* __restrict__ a_dst,
                          float* __restrict__ als, float* __restrict__ ald, int N)
{
    int t = blockIdx.x * blockDim.x + threadIdx.x;
    if (t >= N * 4) return;
    int n = t >> 2, hd = t & 3;
    const unsigned short* hp = h + (size_t)n * HD + hd * 32;
    const float* as = a_src + hd * 32;
    const float* ad = a_dst + hd * 32;
    float s1 = 0.f, s2 = 0.f;
#pragma unroll
    for (int i = 0; i < 32; i += 8) {
        uint4 hv = *(const uint4*)(hp + i);
        unsigned int u[4] = {hv.x, hv.y, hv.z, hv.w};
#pragma unroll
        for (int p = 0; p < 4; p++) {
            float f0 = __uint_as_float(u[p] << 16);
            float f1 = __uint_as_float(u[p] & 0xffff0000u);
            s1 += f0 * as[i + 2 * p] + f1 * as[i + 2 * p + 1];
            s2 += f0 * ad[i + 2 * p] + f1 * ad[i + 2 * p + 1];
        }
    }
    als[t] = s1; ald[t] = s2;
}

// ============================ CSR build (once) ===============================
__global__ void hist_kernel(const int* __restrict__ ei, int E, int N, int* __restrict__ deg)
{
    int t = blockIdx.x * blockDim.x + threadIdx.x;
    if (t >= E + N) return;
    int d = (t < E) ? ei[E + t] : (t - E);
    atomicAdd(&deg[d], 1);
}

__global__ void scan1(const int* __restrict__ deg, int* __restrict__ rp,
                      int* __restrict__ bsum, int N)
{
    __shared__ int sh[256];
    int t = threadIdx.x;
    int i0 = blockIdx.x * 1024 + t * 4;
    int v[4];
#pragma unroll
    for (int j = 0; j < 4; j++) v[j] = (i0 + j < N) ? deg[i0 + j] : 0;
    int tot = v[0] + v[1] + v[2] + v[3];
    sh[t] = tot;
    __syncthreads();
    for (int off = 1; off < 256; off <<= 1) {
        int xv = (t >= off) ? sh[t - off] : 0;
        __syncthreads();
        sh[t] += xv;
        __syncthreads();
    }
    int run = sh[t] - tot;
    if (t == 255) bsum[blockIdx.x] = sh[255];
#pragma unroll
    for (int j = 0; j < 4; j++) {
        if (i0 + j < N) rp[i0 + j] = run;
        run += v[j];
    }
}

__global__ void scan2(int* __restrict__ bsum, int nb)
{
    if (threadIdx.x == 0 && blockIdx.x == 0) {
        int run = 0;
        for (int i = 0; i < nb; i++) { int v = bsum[i]; bsum[i] = run; run += v; }
    }
}

__global__ void scan3(int* __restrict__ rp, int* __restrict__ cur,
                      const int* __restrict__ bsum, int N, int Etot)
{
    int t = blockIdx.x * blockDim.x + threadIdx.x;
    if (t < N) {
        int v = rp[t] + bsum[t >> 10];
        rp[t] = v;
        cur[t] = v;
    } else if (t == N) {
        rp[N] = Etot;
    }
}

__global__ void scatter_kernel(const int* __restrict__ ei, int E, int N,
                               int* __restrict__ cur, int* __restrict__ col)
{
    int t = blockIdx.x * blockDim.x + threadIdx.x;
    if (t >= E + N) return;
    int s, d;
    if (t < E) { s = ei[t]; d = ei[E + t]; } else { s = t - E; d = t - E; }
    int p = atomicAdd(&cur[d], 1);
    col[p] = s;
}

// ============================ aggregation ====================================
// SINGLE-PASS per dst (no max-subtraction: logits ~N(0,sqrt2), |e|<~20, exp
// is fp32-safe; softmax value identical). One wave per dst; lane=(g=lane>>4
// edge-slot, c=lane&15 channel-group, head=c>>2). 4 edges in flight; each
// lane accumulates sum(exp*h[8ch]) AND sum(exp); combine slots via
// shfl_xor(16|32); normalize once at the end. xio fp32 RMW + layer relu.
__global__ __launch_bounds__(256) void agg_kernel(
    const unsigned short* __restrict__ h, const float* __restrict__ als,
    const float* __restrict__ ald, const int* __restrict__ rp,
    const int* __restrict__ col, float* __restrict__ xio, int N)
{
    int wid  = (blockIdx.x * blockDim.x + threadIdx.x) >> 6;
    int lane = threadIdx.x & 63;
    if (wid >= N) return;
    int beg = rp[wid], end = rp[wid + 1];

    int g = lane >> 4, c = lane & 15, hB = c >> 2;
    float ad_h = ald[wid * 4 + hB];
    float acc[8];
#pragma unroll
    for (int p = 0; p < 8; p++) acc[p] = 0.f;
    float wsum = 0.f;
    const unsigned short* hbase = h + c * 8;
    for (int j = beg + g; j < end; j += 4) {
        int s = col[j];
        float e = als[s * 4 + hB] + ad_h;
        e = e > 0.f ? e : NEG_SLOPE * e;
        float wgt = __expf(e);
        wsum += wgt;
        uint4 hv = *(const uint4*)(hbase + (size_t)s * HD);
        unsigned int uu[4] = {hv.x, hv.y, hv.z, hv.w};
#pragma unroll
        for (int p = 0; p < 4; p++) {
            acc[2 * p]     += wgt * __uint_as_float(uu[p] << 16);
            acc[2 * p + 1] += wgt * __uint_as_float(uu[p] & 0xffff0000u);
        }
    }
#pragma unroll
    for (int p = 0; p < 8; p++) {
        acc[p] += __shfl_xor(acc[p], 16);
        acc[p] += __shfl_xor(acc[p], 32);
    }
    wsum += __shfl_xor(wsum, 16);
    wsum += __shfl_xor(wsum, 32);
    if (g == 0) {
        float inv = 1.0f / wsum;
        float* xp = xio + (size_t)wid * HD + c * 8;
        float4 x0 = *(float4*)xp, x1 = *(float4*)(xp + 4);
        float o[8] = {acc[0] * inv + x0.x, acc[1] * inv + x0.y,
                      acc[2] * inv + x0.z, acc[3] * inv + x0.w,
                      acc[4] * inv + x1.x, acc[5] * inv + x1.y,
                      acc[6] * inv + x1.z, acc[7] * inv + x1.w};
#pragma unroll
        for (int p = 0; p < 8; p++) o[p] = o[p] > 0.f ? o[p] : 0.f;
        *(float4*)xp       = (float4){o[0], o[1], o[2], o[3]};
        *(float4*)(xp + 4) = (float4){o[4], o[5], o[6], o[7]};
    }
}

// ============================ classifier =====================================
__global__ __launch_bounds__(256) void cls_kernel(
    const float* __restrict__ x, const float* __restrict__ w,
    const float* __restrict__ b, float* __restrict__ out, int N)
{
    int wid  = (blockIdx.x * blockDim.x + threadIdx.x) >> 6;
    int lane = threadIdx.x & 63;
    if (wid >= N) return;
    float x0 = x[(size_t)wid * HD + lane];
    float x1 = x[(size_t)wid * HD + 64 + lane];
    float acc[10];
#pragma unroll
    for (int o = 0; o < 10; o++)
        acc[o] = x0 * w[lane * 10 + o] + x1 * w[(lane + 64) * 10 + o];
#pragma unroll
    for (int o = 0; o < 10; o++) {
        float v = acc[o];
#pragma unroll
        for (int off = 1; off < 64; off <<= 1) v += __shfl_xor(v, off);
        acc[o] = v;
    }
    float v = 0.f;
#pragma unroll
    for (int o = 0; o < 10; o++) if (lane == o) v = acc[o];
    if (lane < 10) out[(size_t)wid * 10 + lane] = v + b[lane];
}

// =============================================================================
extern "C" void kernel_launch(void* const* d_in, const int* in_sizes, int n_in,
                              void* d_out, int out_size, void* d_ws, size_t ws_size,
                              hipStream_t stream)
{
    const float* x0 = (const float*)d_in[0];
    const int*   ei = (const int*)d_in[1];
    const int N = in_sizes[0] / 512;
    const int E = in_sizes[1] / 2;
    const int Etot = E + N;

    const float *gw[3], *gas[3], *gad[3], *gbp[3], *fw[3], *fbp[3], *fgp[3], *fbt[3];
    for (int l = 0; l < 3; l++) {
        int b = 3 + 8 * l;
        gw[l]  = (const float*)d_in[b + 0];
        gas[l] = (const float*)d_in[b + 1];
        gad[l] = (const float*)d_in[b + 2];
        gbp[l] = (const float*)d_in[b + 3];
        fw[l]  = (const float*)d_in[b + 4];
        fbp[l] = (const float*)d_in[b + 5];
        fgp[l] = (const float*)d_in[b + 6];
        fbt[l] = (const float*)d_in[b + 7];
    }
    const float* cw = (const float*)d_in[27];
    const float* cb = (const float*)d_in[28];

    char* p = (char*)d_ws;
    auto carve = [&](size_t bytes) -> char* {
        char* r = p; p += (bytes + 255) & ~(size_t)255; return r;
    };
    float* xA   = (float*)carve((size_t)N * HD * 4);
    float* xB   = (float*)carve((size_t)N * HD * 4);
    unsigned short* hbuf = (unsigned short*)carve((size_t)N * HD * 2);   // bf16 h
    float* als  = (float*)carve((size_t)N * 4 * 4);
    float* ald  = (float*)carve((size_t)N * 4 * 4);
    int* rp   = (int*)carve((size_t)(N + 1) * 4);
    int* deg  = (int*)carve((size_t)N * 4);
    int* cur  = (int*)carve((size_t)N * 4);
    int* bsum = (int*)carve(4096);
    int* col  = (int*)carve((size_t)Etot * 4);
    unsigned short* wT[3];
    for (int l = 0; l < 3; l++) {
        int K = (l == 0) ? 512 : HD;
        wT[l] = (unsigned short*)carve((size_t)256 * K * 2);
    }

    // ---- weight cast+transpose+concat (tiny) ----
    for (int l = 0; l < 3; l++) {
        int K = (l == 0) ? 512 : HD;
        int nt = K * 256;
        prep_w2<<<(nt + 255) / 256, 256, 0, stream>>>(gw[l], fw[l], wT[l], K);
    }

    // ---- CSR by dst ----
    hipMemsetAsync(deg, 0, (size_t)N * 4, stream);
    hist_kernel<<<(Etot + 255) / 256, 256, 0, stream>>>(ei, E, N, deg);
    int nb = (N + 1023) / 1024;
    scan1<<<nb, 256, 0, stream>>>(deg, rp, bsum, N);
    scan2<<<1, 64, 0, stream>>>(bsum, nb);
    scan3<<<(N + 256) / 256, 256, 0, stream>>>(rp, cur, bsum, N, Etot);
    scatter_kernel<<<(Etot + 255) / 256, 256, 0, stream>>>(ei, E, N, cur, col);

    // ---- 3 message-passing layers ----
    for (int l = 0; l < 3; l++) {
        const float* xin = (l == 0) ? x0 : ((l == 1) ? xA : xB);
        float* xout = (l == 1) ? xB : xA;
        int K = (l == 0) ? 512 : HD;
        int mblocks = (N + 63) / 64;
        gemm_dual<<<mblocks, 256, 0, stream>>>(xin, wT[l], hbuf, xout, N, K,
                                               fbp[l], fgp[l], fbt[l], gbp[l]);
        al_kernel<<<(N * 4 + 255) / 256, 256, 0, stream>>>(hbuf, gas[l], gad[l], als, ald, N);
        agg_kernel<<<(N + 3) / 4, 256, 0, stream>>>(hbuf, als, ald, rp, col, xout, N);
    }

    // ---- classifier ----
    cls_kernel<<<(N + 3) / 4, 256, 0, stream>>>(xA, cw, cb, (float*)d_out, N);
}